// Round 3
// baseline (409.123 us; speedup 1.0000x reference)
//
#include <hip/hip_runtime.h>
#include <hip/hip_bf16.h>

#define HWPX 589824          // 768*768
#define MPIX 2359296         // 4*768*768
#define EPSF 1e-7f
#define PX_PER_BLOCK 16384   // 256 threads * 64 px
#define ITERS 8              // 8 iters * (256 threads * 8 px)

// ws float layout:
// [0] cls_bce_sum  [1] cls_inter  [2] cls_sump
// [3] ch0_bce_sum  [4] ch0_inter  [5] ch0_sump
// [6..21]   a_sum[k]   (sum of log1p(-pc)) for pred channels k=1..16
// [22..37]  sum_p[k]
// [38..293] segD[n*16+k]   n=0..15 (ids 1..16)
// [294..549] segP[n*16+k]
// [550..566] cnt[17] as uint32

__device__ __forceinline__ float wave_sum64(float v) {
    #pragma unroll
    for (int o = 32; o; o >>= 1) v += __shfl_xor(v, o, 64);
    return v;
}

__global__ __launch_bounds__(256, 8) void loss_main(
    const float* __restrict__ pred, const float* __restrict__ cls,
    const int* __restrict__ tm, float* __restrict__ acc,
    unsigned* __restrict__ cnt)
{
    __shared__ float binD[17][64];   // 4.25 KB
    __shared__ float binP[17][64];   // 4.25 KB

    const int tid  = threadIdx.x;
    const int lane = tid & 63;
    const int c = blockIdx.y;          // 0=cls, 1=pred ch0, 2..17=pred ch 1..16
    const long base = (long)blockIdx.x * PX_PER_BLOCK;
    const int b   = (int)(base / HWPX);   // block never straddles a batch (36 blocks/batch)
    const int off = (int)(base % HWPX);

    const int* tptr = tm + (long)b * HWPX + off;
    const float* pptr;
    if (c == 0) pptr = cls + (long)b * HWPX + off;
    else        pptr = pred + ((long)b * 17 + (c - 1)) * (long)HWPX + off;

    if (c != 1) {
        for (int i = tid; i < 17 * 64; i += 256) {
            ((float*)binD)[i] = 0.f;
            ((float*)binP)[i] = 0.f;
        }
        __syncthreads();
    }

    float s0 = 0.f, s1 = 0.f, s2 = 0.f;
    // c>=2: s0 = sum log1p(-pc), s1 = sum p
    // c<2 : s0 = sum (t*logp + (1-t)*log1mp), s1 = sum p*t, s2 = sum p

    for (int it = 0; it < ITERS; ++it) {
        const int o = it * 2048 + tid * 8;
        const float4 pA = *(const float4*)(pptr + o);
        const float4 pB = *(const float4*)(pptr + o + 4);
        const int4   tA = *(const int4*)(tptr + o);
        const int4   tB = *(const int4*)(tptr + o + 4);
        const float p[8] = {pA.x, pA.y, pA.z, pA.w, pB.x, pB.y, pB.z, pB.w};
        const int   t[8] = {tA.x, tA.y, tA.z, tA.w, tB.x, tB.y, tB.z, tB.w};
        #pragma unroll
        for (int j = 0; j < 8; ++j) {
            const float pc  = fminf(fmaxf(p[j], EPSF), 1.0f - EPSF);
            const float lp  = __logf(pc);
            const float l1p = __logf(1.0f - pc);   // exact in this range, matches log1p(-pc)
            if (c >= 2) {
                s0 += l1p;
                s1 += p[j];
                atomicAdd(&binD[t[j]][lane], l1p - lp);  // ds_add_f32, no return -> no chain
                atomicAdd(&binP[t[j]][lane], p[j]);
            } else {
                const bool fg = (c == 0) ? (t[j] > 0) : (t[j] == 0);
                s0 += fg ? lp : l1p;
                s1 += fg ? p[j] : 0.f;
                s2 += p[j];
                if (c == 0) {
                    unsigned (*cw)[64] = (unsigned(*)[64])binD;
                    atomicAdd(&cw[t[j]][lane], 1u);      // ds_add_u32
                }
            }
        }
    }

    // scalar block reduction: butterfly within wave, lane0 of each wave atomics
    s0 = wave_sum64(s0);
    s1 = wave_sum64(s1);

    if (c >= 2) {
        const int k = c - 2;   // 0..15
        if (lane == 0) {
            atomicAdd(&acc[6 + k], s0);
            atomicAdd(&acc[22 + k], s1);
        }
        __syncthreads();
        // tree-reduce the 64 columns of each of the 17 rows
        #pragma unroll
        for (int sh = 5; sh >= 0; --sh) {
            const int s = 1 << sh;
            for (int i = tid; i < 17 * s; i += 256) {
                const int n = i >> sh, cc = i & (s - 1);
                binD[n][cc] += binD[n][cc + s];
                binP[n][cc] += binP[n][cc + s];
            }
            __syncthreads();
        }
        if (tid >= 1 && tid <= 16) {
            atomicAdd(&acc[38 + (tid - 1) * 16 + k], binD[tid][0]);
            atomicAdd(&acc[294 + (tid - 1) * 16 + k], binP[tid][0]);
        }
    } else {
        s2 = wave_sum64(s2);
        const int base3 = (c == 0) ? 0 : 3;
        if (lane == 0) {
            atomicAdd(&acc[base3 + 0], s0);
            atomicAdd(&acc[base3 + 1], s1);
            atomicAdd(&acc[base3 + 2], s2);
        }
        if (c == 0) {
            unsigned (*cw)[64] = (unsigned(*)[64])binD;
            __syncthreads();
            #pragma unroll
            for (int sh = 5; sh >= 0; --sh) {
                const int s = 1 << sh;
                for (int i = tid; i < 17 * s; i += 256) {
                    const int n = i >> sh, cc = i & (s - 1);
                    cw[n][cc] += cw[n][cc + s];
                }
                __syncthreads();
            }
            if (tid < 17) atomicAdd(&cnt[tid], cw[tid][0]);
        }
    }
}

__global__ void loss_final(const float* __restrict__ acc,
                           const unsigned* __restrict__ cnt,
                           float* __restrict__ out)
{
    __shared__ float L[16][16];
    const int tid = threadIdx.x;
    const float Mf = (float)MPIX;

    if (tid < 256) {
        const int n = tid >> 4, k = tid & 15;
        const float A    = -acc[6 + k] / Mf;
        const float segD = acc[38 + n * 16 + k];
        const float segP = acc[294 + n * 16 + k];
        const float sump = acc[22 + k];
        const float cn   = (float)cnt[n + 1];
        const float bce  = A + segD / Mf;
        const float dice = 1.f - (2.f * segP + EPSF) / (sump + cn + EPSF);
        L[n][k] = bce + dice;
    }
    __syncthreads();

    if (tid < 64) {   // wave 0 performs the greedy assignment on lanes 0..15
        const bool mine = (tid < 16);
        float total = 0.f;
        unsigned avail = mine ? 1u : 0u;
        for (int step = 0; step < 16; ++step) {
            float v = (mine && avail) ? L[step][tid] : 1e30f;
            int idx = tid;
            #pragma unroll
            for (int o = 8; o; o >>= 1) {
                const float ov = __shfl_xor(v, o, 64);
                const int   oi = __shfl_xor(idx, o, 64);
                if (ov < v || (ov == v && oi < idx)) { v = ov; idx = oi; }
            }
            if (tid == 0) total += v;
            if (tid == idx) avail = 0;
        }
        if (tid == 0) {
            const float sum_tfg = Mf - (float)cnt[0];
            const float bce_c  = -acc[0] / Mf;
            const float dice_c = 1.f - (2.f * acc[1] + EPSF) / (acc[2] + sum_tfg + EPSF);
            const float bce_0  = -acc[3] / Mf;
            const float dice_0 = 1.f - (2.f * acc[4] + EPSF) / (acc[5] + (float)cnt[0] + EPSF);
            const float res = bce_c + dice_c + bce_0 + dice_0;
            out[0] = (res + total) / 16.f;
        }
    }
}

extern "C" void kernel_launch(void* const* d_in, const int* in_sizes, int n_in,
                              void* d_out, int out_size, void* d_ws, size_t ws_size,
                              hipStream_t stream)
{
    const float* pred = (const float*)d_in[0];
    const float* cls  = (const float*)d_in[1];
    const int*   tmi  = (const int*)d_in[2];
    float*    acc = (float*)d_ws;
    unsigned* cnt = (unsigned*)((char*)d_ws + 550 * sizeof(float));

    hipMemsetAsync(d_ws, 0, (550 + 17) * sizeof(float), stream);

    dim3 grid(MPIX / PX_PER_BLOCK, 18);   // 144 x 18
    loss_main<<<grid, 256, 0, stream>>>(pred, cls, tmi, acc, cnt);
    loss_final<<<1, 256, 0, stream>>>(acc, cnt, (float*)d_out);
}

// Round 4
// 330.580 us; speedup vs baseline: 1.2376x; 1.2376x over previous
//
#include <hip/hip_runtime.h>

#define HWPX 589824          // 768*768
#define MPIX 2359296         // 4*768*768
#define EPSF 1e-7f
#define PX_PER_BLOCK 16384   // 256 threads * 64 px
#define ITERS 8              // 8 iters * (256 threads * 8 px)

// ws float layout:
// [0..2]   cls: bce_sum, inter, sum_p
// [3..5]   pred ch0 vs (1-tfg): bce_sum, inter, sum_p
// [6..21]  a_sum[k]  = sum log1p(-pc), channels k=0..15 (pred ch 1..16)
// [22..37] sum_p[k]
// [38..293]  segD[n*16+k]  n=0..15 (ids 1..16)
// [294..549] segP[n*16+k]
// [550..565] cntf[n]       float counts of ids 1..16

__device__ __forceinline__ float wave_sum64(float v) {
    #pragma unroll
    for (int o = 32; o; o >>= 1) v += __shfl_xor(v, o, 64);
    return v;
}

__global__ __launch_bounds__(256) void loss_main(
    const float* __restrict__ pred, const float* __restrict__ cls,
    const int* __restrict__ tm, float* __restrict__ acc)
{
    const int tid  = threadIdx.x;
    const int lane = tid & 63;
    const int c = blockIdx.y;          // 0=cls, 1=pred ch0, 2..17=pred ch 1..16
    const long base = (long)blockIdx.x * PX_PER_BLOCK;
    const int b   = (int)(base / HWPX);   // 36 blocks/batch, never straddles
    const int off = (int)(base % HWPX);

    const int* tptr = tm + (long)b * HWPX + off;
    const float* pptr = (c == 0) ? (cls + (long)b * HWPX + off)
                                 : (pred + ((long)b * 17 + (c - 1)) * (long)HWPX + off);

    // register bins, ids 1..16 only (segment 0 is dropped by the reference)
    float regD[17], regP[17];
    #pragma unroll
    for (int n = 1; n <= 16; ++n) { regD[n] = 0.f; regP[n] = 0.f; }

    float s0 = 0.f, s1 = 0.f, s2 = 0.f;
    // c>=2: s0 = sum log1p(-pc), s1 = sum p
    // c<2 : s0 = sum (t?logp:log1mp), s1 = sum p*t, s2 = sum p

    for (int it = 0; it < ITERS; ++it) {
        const int o = it * 2048 + tid * 8;
        const float4 pA = *(const float4*)(pptr + o);
        const float4 pB = *(const float4*)(pptr + o + 4);
        const int4   tA = *(const int4*)(tptr + o);
        const int4   tB = *(const int4*)(tptr + o + 4);
        const float p[8] = {pA.x,pA.y,pA.z,pA.w,pB.x,pB.y,pB.z,pB.w};
        const int   t[8] = {tA.x,tA.y,tA.z,tA.w,tB.x,tB.y,tB.z,tB.w};
        #pragma unroll
        for (int j = 0; j < 8; ++j) {
            const float pc  = fminf(fmaxf(p[j], EPSF), 1.0f - EPSF);
            const float lp  = __logf(pc);
            const float l1p = __logf(1.0f - pc);   // exact here, matches log1p(-pc)
            if (c >= 2) {
                s0 += l1p;
                s1 += p[j];
                const float D = l1p - lp;
                #pragma unroll
                for (int n = 1; n <= 16; ++n) {     // branchless select, all-register
                    const float oh = (t[j] == n) ? 1.f : 0.f;
                    regD[n] = fmaf(oh, D,    regD[n]);
                    regP[n] = fmaf(oh, p[j], regP[n]);
                }
            } else {
                const bool fg = (c == 0) ? (t[j] > 0) : (t[j] == 0);
                s0 += fg ? lp : l1p;
                s1 += fg ? p[j] : 0.f;
                s2 += p[j];
                if (c == 0) {
                    #pragma unroll
                    for (int n = 1; n <= 16; ++n)
                        regP[n] += (t[j] == n) ? 1.f : 0.f;   // exact integer counts
                }
            }
        }
    }

    if (c >= 2) {
        const int k = c - 2;   // 0..15
        s0 = wave_sum64(s0);
        s1 = wave_sum64(s1);
        if (lane == 0) {
            atomicAdd(&acc[6 + k], s0);
            atomicAdd(&acc[22 + k], s1);
        }
        #pragma unroll
        for (int n = 1; n <= 16; ++n) {
            const float d = wave_sum64(regD[n]);
            const float q = wave_sum64(regP[n]);
            if (lane == 0) {
                atomicAdd(&acc[38 + (n - 1) * 16 + k], d);
                atomicAdd(&acc[294 + (n - 1) * 16 + k], q);
            }
        }
    } else {
        s0 = wave_sum64(s0);
        s1 = wave_sum64(s1);
        s2 = wave_sum64(s2);
        const int base3 = (c == 0) ? 0 : 3;
        if (lane == 0) {
            atomicAdd(&acc[base3 + 0], s0);
            atomicAdd(&acc[base3 + 1], s1);
            atomicAdd(&acc[base3 + 2], s2);
        }
        if (c == 0) {
            #pragma unroll
            for (int n = 1; n <= 16; ++n) {
                const float q = wave_sum64(regP[n]);
                if (lane == 0) atomicAdd(&acc[550 + (n - 1)], q);
            }
        }
    }
}

__global__ void loss_final(const float* __restrict__ acc, float* __restrict__ out)
{
    __shared__ float L[16][16];
    __shared__ float s_fg;
    const int tid = threadIdx.x;
    const float Mf = (float)MPIX;

    if (tid == 0) {
        float s = 0.f;
        for (int n = 0; n < 16; ++n) s += acc[550 + n];
        s_fg = s;                      // # pixels with id>0 == sum(tfg)
    }
    __syncthreads();

    if (tid < 256) {
        const int n = tid >> 4, k = tid & 15;
        const float A    = -acc[6 + k] / Mf;
        const float segD = acc[38 + n * 16 + k];
        const float segP = acc[294 + n * 16 + k];
        const float sump = acc[22 + k];
        const float cn   = acc[550 + n];
        const float bce  = A + segD / Mf;
        const float dice = 1.f - (2.f * segP + EPSF) / (sump + cn + EPSF);
        L[n][k] = bce + dice;
    }
    __syncthreads();

    if (tid < 64) {   // wave 0: greedy assignment on lanes 0..15
        const bool mine = (tid < 16);
        float total = 0.f;
        unsigned avail = mine ? 1u : 0u;
        for (int step = 0; step < 16; ++step) {
            float v = (mine && avail) ? L[step][tid] : 1e30f;
            int idx = tid;
            #pragma unroll
            for (int o = 8; o; o >>= 1) {
                const float ov = __shfl_xor(v, o, 64);
                const int   oi = __shfl_xor(idx, o, 64);
                if (ov < v || (ov == v && oi < idx)) { v = ov; idx = oi; }
            }
            if (tid == 0) total += v;
            if (tid == idx) avail = 0;
        }
        if (tid == 0) {
            const float cnt0 = Mf - s_fg;
            const float bce_c  = -acc[0] / Mf;
            const float dice_c = 1.f - (2.f * acc[1] + EPSF) / (acc[2] + s_fg + EPSF);
            const float bce_0  = -acc[3] / Mf;
            const float dice_0 = 1.f - (2.f * acc[4] + EPSF) / (acc[5] + cnt0 + EPSF);
            const float res = bce_c + dice_c + bce_0 + dice_0;
            out[0] = (res + total) / 16.f;
        }
    }
}

extern "C" void kernel_launch(void* const* d_in, const int* in_sizes, int n_in,
                              void* d_out, int out_size, void* d_ws, size_t ws_size,
                              hipStream_t stream)
{
    const float* pred = (const float*)d_in[0];
    const float* cls  = (const float*)d_in[1];
    const int*   tmi  = (const int*)d_in[2];
    float* acc = (float*)d_ws;

    hipMemsetAsync(d_ws, 0, 566 * sizeof(float), stream);

    dim3 grid(MPIX / PX_PER_BLOCK, 18);   // 144 x 18
    loss_main<<<grid, 256, 0, stream>>>(pred, cls, tmi, acc);
    loss_final<<<1, 256, 0, stream>>>(acc, (float*)d_out);
}

// Round 5
// 89.337 us; speedup vs baseline: 4.5795x; 3.7004x over previous
//
#include <hip/hip_runtime.h>

#define HWPX 589824          // 768*768
#define MPIX 2359296         // 4*768*768
#define EPSF 1e-7f
#define NBLK 576             // 4096 px/block; 144 blocks/batch -> never straddles a batch
#define PXB  4096
#define MSTEPS 16            // 16 steps * (8 waves * 32 px) = 4096 px

// ws float layout:
// [0..2]   cls: bce_sum, inter, sum_p
// [3..5]   pred ch0 vs (1-tfg): bce_sum, inter, sum_p
// [6..21]  a_sum[k]  = sum log1p(-pc), channels k=0..15 (pred ch 1..16)
// [22..37] sum_p[k]
// [38..293]  segD[n*16+k]
// [294..549] segP[n*16+k]
// [550..565] cntf[n]  float counts of ids 1..16

typedef __attribute__((ext_vector_type(8))) short bf16x8;
typedef __attribute__((ext_vector_type(4))) float f32x4;

__device__ __forceinline__ short f2bf(float x) {     // RNE f32 -> bf16 (no NaNs here)
    union { float f; unsigned u; } v; v.f = x;
    const unsigned r = v.u + 0x7fffu + ((v.u >> 16) & 1u);
    return (short)(r >> 16);
}

__device__ __forceinline__ float wave_sum64(float v) {
#pragma unroll
    for (int o = 32; o; o >>= 1) v += __shfl_xor(v, o, 64);
    return v;
}

__global__ __launch_bounds__(512) void loss_main(
    const float* __restrict__ pred, const float* __restrict__ cls,
    const int* __restrict__ tm, float* __restrict__ acc)
{
    __shared__ float sD[8][256];     // per-wave segD C-frags
    __shared__ float sP[8][256];
    __shared__ float sCh[3][16][8];  // {sum_l1p, sum_p, cnt}[ch/bin][wave]
    __shared__ float sC6[6][8];      // cls/ch0 partials

    const int tid  = threadIdx.x;
    const int w    = tid >> 6;       // wave 0..7
    const int lane = tid & 63;
    const int g    = lane >> 4;      // px subgroup 0..3
    const int q    = lane & 15;      // B: channel idx / A: bin idx

    const long base = (long)blockIdx.x * PXB;
    const int b   = (int)(base / HWPX);
    const int off = (int)(base % HWPX);

    const int*   trow = tm   + (long)b * HWPX + off;
    const float* prow = pred + ((long)b * 17 + 1 + q) * (long)HWPX + off;

    f32x4 aD = {0.f, 0.f, 0.f, 0.f};
    f32x4 aP = {0.f, 0.f, 0.f, 0.f};
    float sl1p = 0.f, sp = 0.f, cf = 0.f;
    const int tgt = q + 1;

    for (int s = 0; s < MSTEPS; ++s) {
        const int pxl = s * 256 + w * 32 + g * 8;
        const float4 pa = *(const float4*)(prow + pxl);
        const float4 pb = *(const float4*)(prow + pxl + 4);
        const int4   ta = *(const int4*)(trow + pxl);
        const int4   tb = *(const int4*)(trow + pxl + 4);
        const float pv[8] = {pa.x,pa.y,pa.z,pa.w,pb.x,pb.y,pb.z,pb.w};
        const int   tv[8] = {ta.x,ta.y,ta.z,ta.w,tb.x,tb.y,tb.z,tb.w};
        bf16x8 av, bD, bP;
#pragma unroll
        for (int j = 0; j < 8; ++j) {
            const float p  = pv[j];
            const float pc = fminf(fmaxf(p, EPSF), 1.0f - EPSF);
            const float lp  = __logf(pc);
            const float l1p = __logf(1.0f - pc);   // exact here, matches log1p(-pc)
            sl1p += l1p;
            sp   += p;
            bD[j] = f2bf(l1p - lp);
            bP[j] = f2bf(p);
            const bool m = (tv[j] == tgt);
            av[j] = m ? (short)0x3F80 : (short)0;  // 1.0bf16 / 0
            cf += m ? 1.f : 0.f;
        }
        // segD[bin][ch] += onehot[bin][px] * D[px][ch]   (A 16x32, B 32x16)
        aD = __builtin_amdgcn_mfma_f32_16x16x32_bf16(av, bD, aD, 0, 0, 0);
        aP = __builtin_amdgcn_mfma_f32_16x16x32_bf16(av, bP, aP, 0, 0, 0);
    }

    // channel/bin-keyed reduction across the 4 px-subgroups (lanes l, l^16, l^32, l^48)
    sl1p += __shfl_xor(sl1p, 16, 64); sl1p += __shfl_xor(sl1p, 32, 64);
    sp   += __shfl_xor(sp,   16, 64); sp   += __shfl_xor(sp,   32, 64);
    cf   += __shfl_xor(cf,   16, 64); cf   += __shfl_xor(cf,   32, 64);
    if (lane < 16) { sCh[0][q][w] = sl1p; sCh[1][q][w] = sp; sCh[2][q][w] = cf; }

    *(f32x4*)&sD[w][lane * 4] = aD;   // element (n,k) at flat ((((n>>2)<<4)|k)<<2)|(n&3)
    *(f32x4*)&sP[w][lane * 4] = aP;
    __syncthreads();

    if (tid < 256) {
        const int n = tid >> 4, k = tid & 15;
        const int idx = ((((n >> 2) << 4) | k) << 2) | (n & 3);
        float dsum = 0.f, psum = 0.f;
#pragma unroll
        for (int ww = 0; ww < 8; ++ww) { dsum += sD[ww][idx]; psum += sP[ww][idx]; }
        atomicAdd(&acc[38 + n * 16 + k], dsum);
        atomicAdd(&acc[294 + n * 16 + k], psum);
    } else if (tid < 304) {
        const int i = tid - 256, qq = i >> 4, ii = i & 15;
        float t = 0.f;
#pragma unroll
        for (int ww = 0; ww < 8; ++ww) t += sCh[qq][ii][ww];
        atomicAdd(&acc[(qq == 0) ? (6 + ii) : (qq == 1) ? (22 + ii) : (550 + ii)], t);
    }

    // ---- cls (vs tfg) and pred ch0 (vs 1-tfg) over the same pixel range ----
    const float* crow = cls  + (long)b * HWPX + off;
    const float* zrow = pred + (long)b * 17 * (long)HWPX + off;   // channel 0
    const int pbase = tid * 8;
    const float4 ca = *(const float4*)(crow + pbase);
    const float4 cb = *(const float4*)(crow + pbase + 4);
    const float4 za = *(const float4*)(zrow + pbase);
    const float4 zb = *(const float4*)(zrow + pbase + 4);
    const int4   ua = *(const int4*)(trow + pbase);
    const int4   ub = *(const int4*)(trow + pbase + 4);
    const float cv[8] = {ca.x,ca.y,ca.z,ca.w,cb.x,cb.y,cb.z,cb.w};
    const float zv[8] = {za.x,za.y,za.z,za.w,zb.x,zb.y,zb.z,zb.w};
    const int   uv[8] = {ua.x,ua.y,ua.z,ua.w,ub.x,ub.y,ub.z,ub.w};
    float s0c=0.f,s1c=0.f,s2c=0.f, s00=0.f,s10=0.f,s20=0.f;
#pragma unroll
    for (int j = 0; j < 8; ++j) {
        const int t = uv[j];
        { const float p = cv[j];
          const float pc = fminf(fmaxf(p, EPSF), 1.0f - EPSF);
          const float lp = __logf(pc), l1p = __logf(1.0f - pc);
          const bool fg = (t > 0);
          s0c += fg ? lp : l1p; s1c += fg ? p : 0.f; s2c += p; }
        { const float p = zv[j];
          const float pc = fminf(fmaxf(p, EPSF), 1.0f - EPSF);
          const float lp = __logf(pc), l1p = __logf(1.0f - pc);
          const bool bg = (t == 0);
          s00 += bg ? lp : l1p; s10 += bg ? p : 0.f; s20 += p; }
    }
    s0c = wave_sum64(s0c); s1c = wave_sum64(s1c); s2c = wave_sum64(s2c);
    s00 = wave_sum64(s00); s10 = wave_sum64(s10); s20 = wave_sum64(s20);
    if (lane == 0) {
        sC6[0][w]=s0c; sC6[1][w]=s1c; sC6[2][w]=s2c;
        sC6[3][w]=s00; sC6[4][w]=s10; sC6[5][w]=s20;
    }
    __syncthreads();
    if (tid < 6) {
        float t = 0.f;
#pragma unroll
        for (int ww = 0; ww < 8; ++ww) t += sC6[tid][ww];
        atomicAdd(&acc[tid], t);
    }
}

__global__ void loss_final(const float* __restrict__ acc, float* __restrict__ out)
{
    __shared__ float L[16][16];
    __shared__ float s_fg;
    const int tid = threadIdx.x;
    const float Mf = (float)MPIX;

    if (tid == 0) {
        float s = 0.f;
        for (int n = 0; n < 16; ++n) s += acc[550 + n];
        s_fg = s;                      // # pixels with id>0 == sum(tfg)
    }
    __syncthreads();

    if (tid < 256) {
        const int n = tid >> 4, k = tid & 15;
        const float A    = -acc[6 + k] / Mf;
        const float segD = acc[38 + n * 16 + k];
        const float segP = acc[294 + n * 16 + k];
        const float sump = acc[22 + k];
        const float cn   = acc[550 + n];
        const float bce  = A + segD / Mf;
        const float dice = 1.f - (2.f * segP + EPSF) / (sump + cn + EPSF);
        L[n][k] = bce + dice;
    }
    __syncthreads();

    if (tid < 64) {   // wave 0: greedy assignment on lanes 0..15
        const bool mine = (tid < 16);
        float total = 0.f;
        unsigned avail = mine ? 1u : 0u;
        for (int step = 0; step < 16; ++step) {
            float v = (mine && avail) ? L[step][tid] : 1e30f;
            int idx = tid;
            #pragma unroll
            for (int o = 8; o; o >>= 1) {
                const float ov = __shfl_xor(v, o, 64);
                const int   oi = __shfl_xor(idx, o, 64);
                if (ov < v || (ov == v && oi < idx)) { v = ov; idx = oi; }
            }
            if (tid == 0) total += v;
            if (tid == idx) avail = 0;
        }
        if (tid == 0) {
            const float cnt0 = Mf - s_fg;
            const float bce_c  = -acc[0] / Mf;
            const float dice_c = 1.f - (2.f * acc[1] + EPSF) / (acc[2] + s_fg + EPSF);
            const float bce_0  = -acc[3] / Mf;
            const float dice_0 = 1.f - (2.f * acc[4] + EPSF) / (acc[5] + cnt0 + EPSF);
            const float res = bce_c + dice_c + bce_0 + dice_0;
            out[0] = (res + total) / 16.f;
        }
    }
}

extern "C" void kernel_launch(void* const* d_in, const int* in_sizes, int n_in,
                              void* d_out, int out_size, void* d_ws, size_t ws_size,
                              hipStream_t stream)
{
    const float* pred = (const float*)d_in[0];
    const float* cls  = (const float*)d_in[1];
    const int*   tmi  = (const int*)d_in[2];
    float* acc = (float*)d_ws;

    hipMemsetAsync(d_ws, 0, 566 * sizeof(float), stream);

    loss_main<<<dim3(NBLK), 512, 0, stream>>>(pred, cls, tmi, acc);
    loss_final<<<1, 256, 0, stream>>>(acc, (float*)d_out);
}

// Round 6
// 76.201 us; speedup vs baseline: 5.3690x; 1.1724x over previous
//
#include <hip/hip_runtime.h>
#include <hip/hip_bf16.h>

#define HWPX 589824          // 768*768
#define MPIX 2359296         // 4*768*768
#define EPSF 1e-7f
#define LN2F 0.6931471805599453f
#define PXB  2048            // px per block; 288 blocks/batch -> never straddles
#define NBLK 1152            // MPIX / PXB
#define MSTEPS 8             // 8 steps * (8 waves * 32 px) = 2048 px

// ws float layout:
// [0..2]   cls: bce_log2sum, inter, sum_p
// [3..5]   pred ch0 vs (1-tfg): bce_log2sum, inter, sum_p
// [6..21]  a_sum[k]  = sum log2(1-pc), channels k=0..15 (pred ch 1..16)
// [22..37] sum_p[k]
// [38..293]  segD[n*16+k]   (log2 units)
// [294..549] segP[n*16+k]
// [550..565] cntf[n]  float counts of ids 1..16

typedef __attribute__((ext_vector_type(8))) short bf16x8;
typedef __attribute__((ext_vector_type(4))) float f32x4;

__device__ __forceinline__ short bfc(float x) {   // compiler emits v_cvt_pk_bf16_f32
    union { __hip_bfloat16 h; short s; } u;
    u.h = __float2bfloat16(x);
    return u.s;
}

__device__ __forceinline__ float wave_sum64(float v) {
#pragma unroll
    for (int o = 32; o; o >>= 1) v += __shfl_xor(v, o, 64);
    return v;
}

__global__ __launch_bounds__(512, 8) void loss_main(
    const float* __restrict__ pred, const float* __restrict__ cls,
    const int* __restrict__ tm, float* __restrict__ acc)
{
    __shared__ float sD[8][256];     // per-wave segD C-frags
    __shared__ float sP[8][256];
    __shared__ float sCh[3][16][8];  // {sum_log2_1mp, sum_p, cnt}[ch/bin][wave]
    __shared__ float sC6[6][8];      // cls/ch0 partials

    const int tid  = threadIdx.x;
    const int w    = tid >> 6;       // wave 0..7
    const int lane = tid & 63;
    const int g    = lane >> 4;      // px subgroup 0..3
    const int q    = lane & 15;      // B: channel idx / A: bin idx

    const long base = (long)blockIdx.x * PXB;
    const int b   = (int)(base / HWPX);
    const int off = (int)(base % HWPX);

    const int*   trow = tm   + (long)b * HWPX + off;
    const float* prow = pred + ((long)b * 17 + 1 + q) * (long)HWPX + off;

    f32x4 aD = {0.f, 0.f, 0.f, 0.f};
    f32x4 aP = {0.f, 0.f, 0.f, 0.f};
    float sl2 = 0.f, sp = 0.f, cf = 0.f;
    const int tgt = q + 1;

    // manual 1-deep pipeline: step s+1's loads issue before step s's math
    int pxl = w * 32 + g * 8;
    float4 pa = *(const float4*)(prow + pxl);
    float4 pb = *(const float4*)(prow + pxl + 4);
    int4   ta = *(const int4*)(trow + pxl);
    int4   tb = *(const int4*)(trow + pxl + 4);

#pragma unroll 1
    for (int s = 0; s < MSTEPS; ++s) {
        const int nx = (s + 1 < MSTEPS) ? pxl + 256 : pxl;   // last iter: dummy reload
        const float4 npa = *(const float4*)(prow + nx);
        const float4 npb = *(const float4*)(prow + nx + 4);
        const int4   nta = *(const int4*)(trow + nx);
        const int4   ntb = *(const int4*)(trow + nx + 4);

        const float pv[8] = {pa.x,pa.y,pa.z,pa.w,pb.x,pb.y,pb.z,pb.w};
        const int   tv[8] = {ta.x,ta.y,ta.z,ta.w,tb.x,tb.y,tb.z,tb.w};
        bf16x8 av, bD, bP;
#pragma unroll
        for (int j = 0; j < 8; ++j) {
            const float p  = pv[j];
            const float pc = fminf(fmaxf(p, EPSF), 1.0f - EPSF);
            const float l2p  = __log2f(pc);          // raw v_log_f32, no ln2 mul
            const float l21p = __log2f(1.0f - pc);
            sl2 += l21p;
            sp  += p;
            bD[j] = bfc(l21p - l2p);                 // log2-units; scaled by ln2 in finalize
            bP[j] = bfc(p);
            const bool m = (tv[j] == tgt);
            av[j] = m ? (short)0x3F80 : (short)0;
            cf += m ? 1.f : 0.f;
        }
        aD = __builtin_amdgcn_mfma_f32_16x16x32_bf16(av, bD, aD, 0, 0, 0);
        aP = __builtin_amdgcn_mfma_f32_16x16x32_bf16(av, bP, aP, 0, 0, 0);
        pa = npa; pb = npb; ta = nta; tb = ntb;
        pxl += 256;
    }

    // reduce per-channel scalars across the 4 px-subgroups (lanes l, l^16, l^32, l^48)
    sl2 += __shfl_xor(sl2, 16, 64); sl2 += __shfl_xor(sl2, 32, 64);
    sp  += __shfl_xor(sp,  16, 64); sp  += __shfl_xor(sp,  32, 64);
    cf  += __shfl_xor(cf,  16, 64); cf  += __shfl_xor(cf,  32, 64);
    if (lane < 16) { sCh[0][q][w] = sl2; sCh[1][q][w] = sp; sCh[2][q][w] = cf; }

    *(f32x4*)&sD[w][lane * 4] = aD;   // element (n,k) at flat ((((n>>2)<<4)|k)<<2)|(n&3)
    *(f32x4*)&sP[w][lane * 4] = aP;

    // ---- cls (vs tfg) and pred ch0 (vs 1-tfg), fused before the barrier ----
    const float* crow = cls  + (long)b * HWPX + off;
    const float* zrow = pred + (long)b * 17 * (long)HWPX + off;   // channel 0
    const int pbase = tid * 4;
    const float4 ca = *(const float4*)(crow + pbase);
    const float4 za = *(const float4*)(zrow + pbase);
    const int4   ua = *(const int4*)(trow + pbase);
    const float cv[4] = {ca.x,ca.y,ca.z,ca.w};
    const float zv[4] = {za.x,za.y,za.z,za.w};
    const int   uv[4] = {ua.x,ua.y,ua.z,ua.w};
    float s0c=0.f,s1c=0.f,s2c=0.f, s00=0.f,s10=0.f,s20=0.f;
#pragma unroll
    for (int j = 0; j < 4; ++j) {
        const int t = uv[j];
        { const float p = cv[j];
          const float pc = fminf(fmaxf(p, EPSF), 1.0f - EPSF);
          const float lp = __log2f(pc), l1p = __log2f(1.0f - pc);
          const bool fg = (t > 0);
          s0c += fg ? lp : l1p; s1c += fg ? p : 0.f; s2c += p; }
        { const float p = zv[j];
          const float pc = fminf(fmaxf(p, EPSF), 1.0f - EPSF);
          const float lp = __log2f(pc), l1p = __log2f(1.0f - pc);
          const bool bg = (t == 0);
          s00 += bg ? lp : l1p; s10 += bg ? p : 0.f; s20 += p; }
    }
    s0c = wave_sum64(s0c); s1c = wave_sum64(s1c); s2c = wave_sum64(s2c);
    s00 = wave_sum64(s00); s10 = wave_sum64(s10); s20 = wave_sum64(s20);
    if (lane == 0) {
        sC6[0][w]=s0c; sC6[1][w]=s1c; sC6[2][w]=s2c;
        sC6[3][w]=s00; sC6[4][w]=s10; sC6[5][w]=s20;
    }
    __syncthreads();

    if (tid < 256) {
        const int n = tid >> 4, k = tid & 15;
        const int idx = ((((n >> 2) << 4) | k) << 2) | (n & 3);
        float dsum = 0.f, psum = 0.f;
#pragma unroll
        for (int ww = 0; ww < 8; ++ww) { dsum += sD[ww][idx]; psum += sP[ww][idx]; }
        atomicAdd(&acc[38 + n * 16 + k], dsum);
        atomicAdd(&acc[294 + n * 16 + k], psum);
    } else if (tid < 304) {
        const int i = tid - 256, qq = i >> 4, ii = i & 15;
        float t = 0.f;
#pragma unroll
        for (int ww = 0; ww < 8; ++ww) t += sCh[qq][ii][ww];
        atomicAdd(&acc[(qq == 0) ? (6 + ii) : (qq == 1) ? (22 + ii) : (550 + ii)], t);
    } else if (tid < 310) {
        const int i = tid - 304;
        float t = 0.f;
#pragma unroll
        for (int ww = 0; ww < 8; ++ww) t += sC6[i][ww];
        atomicAdd(&acc[i], t);
    }
}

__global__ void loss_final(const float* __restrict__ acc, float* __restrict__ out)
{
    __shared__ float L[16][16];
    __shared__ float s_fg;
    const int tid = threadIdx.x;
    const float Mf = (float)MPIX;

    if (tid == 0) {
        float s = 0.f;
        for (int n = 0; n < 16; ++n) s += acc[550 + n];
        s_fg = s;                      // # pixels with id>0 == sum(tfg)
    }
    __syncthreads();

    if (tid < 256) {
        const int n = tid >> 4, k = tid & 15;
        const float segD = acc[38 + n * 16 + k];    // log2 units
        const float segP = acc[294 + n * 16 + k];
        const float sump = acc[22 + k];
        const float cn   = acc[550 + n];
        const float bce  = (segD - acc[6 + k]) * LN2F / Mf;
        const float dice = 1.f - (2.f * segP + EPSF) / (sump + cn + EPSF);
        L[n][k] = bce + dice;
    }
    __syncthreads();

    if (tid < 64) {   // wave 0: greedy assignment on lanes 0..15
        const bool mine = (tid < 16);
        float total = 0.f;
        unsigned avail = mine ? 1u : 0u;
        for (int step = 0; step < 16; ++step) {
            float v = (mine && avail) ? L[step][tid] : 1e30f;
            int idx = tid;
            #pragma unroll
            for (int o = 8; o; o >>= 1) {
                const float ov = __shfl_xor(v, o, 64);
                const int   oi = __shfl_xor(idx, o, 64);
                if (ov < v || (ov == v && oi < idx)) { v = ov; idx = oi; }
            }
            if (tid == 0) total += v;
            if (tid == idx) avail = 0;
        }
        if (tid == 0) {
            const float cnt0 = Mf - s_fg;
            const float bce_c  = -acc[0] * LN2F / Mf;
            const float dice_c = 1.f - (2.f * acc[1] + EPSF) / (acc[2] + s_fg + EPSF);
            const float bce_0  = -acc[3] * LN2F / Mf;
            const float dice_0 = 1.f - (2.f * acc[4] + EPSF) / (acc[5] + cnt0 + EPSF);
            const float res = bce_c + dice_c + bce_0 + dice_0;
            out[0] = (res + total) / 16.f;
        }
    }
}

extern "C" void kernel_launch(void* const* d_in, const int* in_sizes, int n_in,
                              void* d_out, int out_size, void* d_ws, size_t ws_size,
                              hipStream_t stream)
{
    const float* pred = (const float*)d_in[0];
    const float* cls  = (const float*)d_in[1];
    const int*   tmi  = (const int*)d_in[2];
    float* acc = (float*)d_ws;

    hipMemsetAsync(d_ws, 0, 566 * sizeof(float), stream);

    loss_main<<<dim3(NBLK), 512, 0, stream>>>(pred, cls, tmi, acc);
    loss_final<<<1, 256, 0, stream>>>(acc, (float*)d_out);
}

// Round 7
// 69.643 us; speedup vs baseline: 5.8745x; 1.0942x over previous
//
#include <hip/hip_runtime.h>
#include <hip/hip_bf16.h>

#define HWPX 589824          // 768*768
#define MPIX 2359296         // 4*768*768
#define EPSF 1e-7f
#define LN2F 0.6931471805599453f
#define PXB  2304            // px per block; 256 blocks/image -> never straddles
#define NBLK 1024            // MPIX / PXB = 4 blocks/CU exactly
#define MSTEPS 9             // 9 steps * (8 waves * 32 px) = 2304 px

// ws float layout:
// [0..2]   cls: bce_log2sum, inter, sum_p
// [3..5]   pred ch0 vs (1-tfg): bce_log2sum, inter, sum_p
// [6..21]  a_sum[k]  = sum log2(1-pc), channels k=0..15 (pred ch 1..16)
// [22..37] sum_p[k]
// [38..293]  segD[n*16+k]   (log2 units)
// [294..549] segP[n*16+k]
// [550..565] cntf[n]  float counts of ids 1..16

typedef __attribute__((ext_vector_type(8))) short bf16x8;
typedef __attribute__((ext_vector_type(4))) float f32x4;

__device__ __forceinline__ short bfc(float x) {   // compiler emits v_cvt_pk_bf16_f32
    union { __hip_bfloat16 h; short s; } u;
    u.h = __float2bfloat16(x);
    return u.s;
}

__device__ __forceinline__ float wave_sum64(float v) {
#pragma unroll
    for (int o = 32; o; o >>= 1) v += __shfl_xor(v, o, 64);
    return v;
}

__global__ __launch_bounds__(512, 8) void loss_main(
    const float* __restrict__ pred, const float* __restrict__ cls,
    const int* __restrict__ tm, float* __restrict__ acc)
{
    __shared__ float sD[8][256];     // per-wave segD C-frags
    __shared__ float sP[8][256];
    __shared__ float sCh[3][16][8];  // {sum_log2_1mp, sum_p, cnt}[ch/bin][wave]
    __shared__ float sC6[6][8];      // cls/ch0 partials

    const int tid  = threadIdx.x;
    const int w    = tid >> 6;       // wave 0..7
    const int lane = tid & 63;
    const int g    = lane >> 4;      // px subgroup 0..3
    const int q    = lane & 15;      // B: channel idx / A: bin idx

    const long base = (long)blockIdx.x * PXB;
    const int b   = (int)(base / HWPX);
    const int off = (int)(base % HWPX);

    const int*   trow = tm   + (long)b * HWPX + off;
    const float* prow = pred + ((long)b * 17 + 1 + q) * (long)HWPX + off;

    f32x4 aD = {0.f, 0.f, 0.f, 0.f};
    f32x4 aP = {0.f, 0.f, 0.f, 0.f};
    float sl2 = 0.f, sp = 0.f, cf = 0.f;
    const int tgt = q + 1;
    const int lbase = w * 32 + g * 8;

    // fully unrolled: SSA form, no register rotation, no per-step vmcnt(0);
    // compiler hoists loads for several steps ahead within the VGPR budget.
#pragma unroll
    for (int s = 0; s < MSTEPS; ++s) {
        const int pxl = lbase + s * 256;
        const float4 pa = *(const float4*)(prow + pxl);
        const float4 pb = *(const float4*)(prow + pxl + 4);
        const int4   ta = *(const int4*)(trow + pxl);
        const int4   tb = *(const int4*)(trow + pxl + 4);
        const float pv[8] = {pa.x,pa.y,pa.z,pa.w,pb.x,pb.y,pb.z,pb.w};
        const int   tv[8] = {ta.x,ta.y,ta.z,ta.w,tb.x,tb.y,tb.z,tb.w};
        bf16x8 av, bD, bP;
#pragma unroll
        for (int j = 0; j < 8; ++j) {
            const float p  = pv[j];
            const float pc = fminf(fmaxf(p, EPSF), 1.0f - EPSF);
            const float l2p  = __log2f(pc);          // raw v_log_f32
            const float l21p = __log2f(1.0f - pc);
            sl2 += l21p;
            sp  += p;
            bD[j] = bfc(l21p - l2p);                 // log2-units; ln2 applied in finalize
            bP[j] = bfc(p);
            const bool m = (tv[j] == tgt);
            av[j] = m ? (short)0x3F80 : (short)0;
            cf += m ? 1.f : 0.f;
        }
        aD = __builtin_amdgcn_mfma_f32_16x16x32_bf16(av, bD, aD, 0, 0, 0);
        aP = __builtin_amdgcn_mfma_f32_16x16x32_bf16(av, bP, aP, 0, 0, 0);
    }

    // reduce per-channel scalars across the 4 px-subgroups (lanes l, l^16, l^32, l^48)
    sl2 += __shfl_xor(sl2, 16, 64); sl2 += __shfl_xor(sl2, 32, 64);
    sp  += __shfl_xor(sp,  16, 64); sp  += __shfl_xor(sp,  32, 64);
    cf  += __shfl_xor(cf,  16, 64); cf  += __shfl_xor(cf,  32, 64);
    if (lane < 16) { sCh[0][q][w] = sl2; sCh[1][q][w] = sp; sCh[2][q][w] = cf; }

    *(f32x4*)&sD[w][lane * 4] = aD;   // element (n,k) at flat ((((n>>2)<<4)|k)<<2)|(n&3)
    *(f32x4*)&sP[w][lane * 4] = aP;

    // ---- cls (vs tfg) and pred ch0 (vs 1-tfg): 2304 px = 512*4 + 64*4 ----
    const float* crow = cls  + (long)b * HWPX + off;
    const float* zrow = pred + (long)b * 17 * (long)HWPX + off;   // channel 0
    float s0c=0.f,s1c=0.f,s2c=0.f, s00=0.f,s10=0.f,s20=0.f;
    const int nch = (tid < 64) ? 2 : 1;
    for (int chunk = 0; chunk < nch; ++chunk) {
        const int pbase = (chunk == 0) ? tid * 4 : 2048 + tid * 4;
        const float4 ca = *(const float4*)(crow + pbase);
        const float4 za = *(const float4*)(zrow + pbase);
        const int4   ua = *(const int4*)(trow + pbase);
        const float cv[4] = {ca.x,ca.y,ca.z,ca.w};
        const float zv[4] = {za.x,za.y,za.z,za.w};
        const int   uv[4] = {ua.x,ua.y,ua.z,ua.w};
#pragma unroll
        for (int j = 0; j < 4; ++j) {
            const int t = uv[j];
            { const float p = cv[j];
              const float pc = fminf(fmaxf(p, EPSF), 1.0f - EPSF);
              const float lp = __log2f(pc), l1p = __log2f(1.0f - pc);
              const bool fg = (t > 0);
              s0c += fg ? lp : l1p; s1c += fg ? p : 0.f; s2c += p; }
            { const float p = zv[j];
              const float pc = fminf(fmaxf(p, EPSF), 1.0f - EPSF);
              const float lp = __log2f(pc), l1p = __log2f(1.0f - pc);
              const bool bg = (t == 0);
              s00 += bg ? lp : l1p; s10 += bg ? p : 0.f; s20 += p; }
        }
    }
    s0c = wave_sum64(s0c); s1c = wave_sum64(s1c); s2c = wave_sum64(s2c);
    s00 = wave_sum64(s00); s10 = wave_sum64(s10); s20 = wave_sum64(s20);
    if (lane == 0) {
        sC6[0][w]=s0c; sC6[1][w]=s1c; sC6[2][w]=s2c;
        sC6[3][w]=s00; sC6[4][w]=s10; sC6[5][w]=s20;
    }
    __syncthreads();

    if (tid < 256) {
        const int n = tid >> 4, k = tid & 15;
        const int idx = ((((n >> 2) << 4) | k) << 2) | (n & 3);
        float dsum = 0.f, psum = 0.f;
#pragma unroll
        for (int ww = 0; ww < 8; ++ww) { dsum += sD[ww][idx]; psum += sP[ww][idx]; }
        atomicAdd(&acc[38 + n * 16 + k], dsum);
        atomicAdd(&acc[294 + n * 16 + k], psum);
    } else if (tid < 304) {
        const int i = tid - 256, qq = i >> 4, ii = i & 15;
        float t = 0.f;
#pragma unroll
        for (int ww = 0; ww < 8; ++ww) t += sCh[qq][ii][ww];
        atomicAdd(&acc[(qq == 0) ? (6 + ii) : (qq == 1) ? (22 + ii) : (550 + ii)], t);
    } else if (tid < 310) {
        const int i = tid - 304;
        float t = 0.f;
#pragma unroll
        for (int ww = 0; ww < 8; ++ww) t += sC6[i][ww];
        atomicAdd(&acc[i], t);
    }
}

__global__ void loss_final(const float* __restrict__ acc, float* __restrict__ out)
{
    __shared__ float L[16][16];
    __shared__ float s_fg;
    const int tid = threadIdx.x;
    const float Mf = (float)MPIX;

    if (tid == 0) {
        float s = 0.f;
        for (int n = 0; n < 16; ++n) s += acc[550 + n];
        s_fg = s;                      // # pixels with id>0 == sum(tfg)
    }
    __syncthreads();

    if (tid < 256) {
        const int n = tid >> 4, k = tid & 15;
        const float segD = acc[38 + n * 16 + k];    // log2 units
        const float segP = acc[294 + n * 16 + k];
        const float sump = acc[22 + k];
        const float cn   = acc[550 + n];
        const float bce  = (segD - acc[6 + k]) * LN2F / Mf;
        const float dice = 1.f - (2.f * segP + EPSF) / (sump + cn + EPSF);
        L[n][k] = bce + dice;
    }
    __syncthreads();

    if (tid < 64) {   // wave 0: greedy assignment on lanes 0..15
        const bool mine = (tid < 16);
        float total = 0.f;
        unsigned avail = mine ? 1u : 0u;
        for (int step = 0; step < 16; ++step) {
            float v = (mine && avail) ? L[step][tid] : 1e30f;
            int idx = tid;
            #pragma unroll
            for (int o = 8; o; o >>= 1) {
                const float ov = __shfl_xor(v, o, 64);
                const int   oi = __shfl_xor(idx, o, 64);
                if (ov < v || (ov == v && oi < idx)) { v = ov; idx = oi; }
            }
            if (tid == 0) total += v;
            if (tid == idx) avail = 0;
        }
        if (tid == 0) {
            const float cnt0 = Mf - s_fg;
            const float bce_c  = -acc[0] * LN2F / Mf;
            const float dice_c = 1.f - (2.f * acc[1] + EPSF) / (acc[2] + s_fg + EPSF);
            const float bce_0  = -acc[3] * LN2F / Mf;
            const float dice_0 = 1.f - (2.f * acc[4] + EPSF) / (acc[5] + cnt0 + EPSF);
            const float res = bce_c + dice_c + bce_0 + dice_0;
            out[0] = (res + total) / 16.f;
        }
    }
}

extern "C" void kernel_launch(void* const* d_in, const int* in_sizes, int n_in,
                              void* d_out, int out_size, void* d_ws, size_t ws_size,
                              hipStream_t stream)
{
    const float* pred = (const float*)d_in[0];
    const float* cls  = (const float*)d_in[1];
    const int*   tmi  = (const int*)d_in[2];
    float* acc = (float*)d_ws;

    hipMemsetAsync(d_ws, 0, 566 * sizeof(float), stream);

    loss_main<<<dim3(NBLK), 512, 0, stream>>>(pred, cls, tmi, acc);
    loss_final<<<1, 256, 0, stream>>>(acc, (float*)d_out);
}